// Round 1
// baseline (412.504 us; speedup 1.0000x reference)
//
#include <hip/hip_runtime.h>
#include <hip/hip_bf16.h>

typedef __bf16 bf16x8 __attribute__((ext_vector_type(8)));
typedef float f32x4 __attribute__((ext_vector_type(4)));

#define DEVINL __device__ __forceinline__

DEVINL void gload16(void* lds, const void* g) {
  __builtin_amdgcn_global_load_lds((const __attribute__((address_space(1))) void*)g,
                                   (__attribute__((address_space(3))) void*)lds, 16, 0, 0);
}

// ---------------- weight cast+transpose: in [R][C] fp32 -> out [C][R] bf16 ----------------
__global__ __launch_bounds__(256)
void transpose_cast(const float* __restrict__ in, __bf16* __restrict__ out, int R, int C)
{
  __shared__ __bf16 tile[32][33];
  const int bc = blockIdx.x * 32, br = blockIdx.y * 32;
  const int lx = threadIdx.x & 31, ly = threadIdx.x >> 5;
#pragma unroll
  for (int p = 0; p < 4; ++p)
    tile[ly + p * 8][lx] = (__bf16)in[(size_t)(br + ly + p * 8) * C + bc + lx];
  __syncthreads();
#pragma unroll
  for (int p = 0; p < 4; ++p)
    out[(size_t)(bc + ly + p * 8) * R + br + lx] = tile[lx][ly + p * 8];
}

// ---------------- elementwise cast fp32 -> bf16 ----------------
__global__ __launch_bounds__(256)
void cast_bf16(const float* __restrict__ in, __bf16* __restrict__ out)
{
  const int i = (blockIdx.x * 256 + threadIdx.x) * 4;
  float4 v = *(const float4*)(in + i);
  out[i] = (__bf16)v.x; out[i + 1] = (__bf16)v.y;
  out[i + 2] = (__bf16)v.z; out[i + 3] = (__bf16)v.w;
}

// ---------------- bf16 MFMA GEMM: C[M][N] = A[M][K] @ Bt[N][K]^T + bias (+resid)(+relu) ----
template<bool OUT_BF16, bool RELU, bool RESID>
__global__ __launch_bounds__(256)
void gemm_bt(const __bf16* __restrict__ A, const __bf16* __restrict__ Bt,
             const float* __restrict__ bias, const float* __restrict__ resid,
             void* __restrict__ Cv, int M, int N, int K)
{
  __shared__ __bf16 As[128 * 32];
  __shared__ __bf16 Bs[128 * 32];
  const int tid = threadIdx.x;
  const int wave = tid >> 6, lane = tid & 63;
  const int g = lane >> 4, l16 = lane & 15;
  const int row0 = blockIdx.x * 128, col0 = blockIdx.y * 128;
  const int wr = wave >> 1, wc = wave & 1;
  f32x4 acc[4][4] = {};
  for (int k0 = 0; k0 < K; k0 += 32) {
    __syncthreads();
#pragma unroll
    for (int r = 0; r < 2; ++r) {
      const int seg = r * 256 + tid;
      const int arow = seg >> 2, ko = (seg & 3) * 8;
      gload16(&As[(r * 256 + wave * 64) * 8], &A[(size_t)(row0 + arow) * K + k0 + ko]);
      gload16(&Bs[(r * 256 + wave * 64) * 8], &Bt[(size_t)(col0 + arow) * K + k0 + ko]);
    }
    __syncthreads();
    bf16x8 af[4], bfr[4];
#pragma unroll
    for (int m = 0; m < 4; ++m)
      af[m] = *(const bf16x8*)&As[(wr * 64 + m * 16 + l16) * 32 + g * 8];
#pragma unroll
    for (int n = 0; n < 4; ++n)
      bfr[n] = *(const bf16x8*)&Bs[(wc * 64 + n * 16 + l16) * 32 + g * 8];
#pragma unroll
    for (int m = 0; m < 4; ++m)
#pragma unroll
      for (int n = 0; n < 4; ++n)
        acc[m][n] = __builtin_amdgcn_mfma_f32_16x16x32_bf16(af[m], bfr[n], acc[m][n], 0, 0, 0);
  }
#pragma unroll
  for (int n = 0; n < 4; ++n) {
    const int col = col0 + wc * 64 + n * 16 + l16;
    const float bv = bias[col];
#pragma unroll
    for (int m = 0; m < 4; ++m) {
      const int rrow = row0 + wr * 64 + m * 16 + g * 4;
#pragma unroll
      for (int r = 0; r < 4; ++r) {
        float v = acc[m][n][r] + bv;
        if (RESID) v += resid[(size_t)(rrow + r) * N + col];
        if (RELU)  v = fmaxf(v, 0.f);
        if (OUT_BF16) ((__bf16*)Cv)[(size_t)(rrow + r) * N + col] = (__bf16)v;
        else          ((float*)Cv)[(size_t)(rrow + r) * N + col] = v;
      }
    }
  }
}

// ---------------- flash attention (causal), bf16 MFMA ----------------
// grid (S/128, B*NH), 256 thr. qkv: [B*S][3H] bf16 (q|k|v). ctx: [B*S][H] bf16.
__global__ __launch_bounds__(256)
void attn_fwd(const __bf16* __restrict__ qkv, __bf16* __restrict__ ctx)
{
  constexpr int S = 2048, H = 1024, W3 = 3 * H;
  __shared__ __bf16 Ks[64 * 64];
  __shared__ __bf16 Vt[64 * 64];
  __shared__ __bf16 Ps[4][32 * 64];
  const int tid = threadIdx.x, wave = tid >> 6, lane = tid & 63;
  const int g = lane >> 4, l16 = lane & 15;
  const int q0 = blockIdx.x * 128;
  const int bh = blockIdx.y;
  const int b = bh >> 4, h = bh & 15;
  const size_t base = (size_t)b * S * W3;
  const __bf16* Qg = qkv + base;
  const __bf16* Kg = qkv + base + H;
  const __bf16* Vg = qkv + base + 2 * H;

  bf16x8 qa[2][2];
#pragma unroll
  for (int m = 0; m < 2; ++m)
#pragma unroll
    for (int kk = 0; kk < 2; ++kk)
      qa[m][kk] = *(const bf16x8*)&Qg[(size_t)(q0 + wave * 32 + m * 16 + l16) * W3 + h * 64 + kk * 32 + g * 8];

  f32x4 o[2][4] = {};
  float mr[2][4], lr[2][4];
#pragma unroll
  for (int m = 0; m < 2; ++m)
#pragma unroll
    for (int r = 0; r < 4; ++r) { mr[m][r] = -1e30f; lr[m][r] = 0.f; }

  const int qmax = q0 + wave * 32 + 31;
  const int nT = (q0 + 127) / 64 + 1;

  for (int t = 0; t < nT; ++t) {
    const int kv0 = t * 64;
    __syncthreads();
#pragma unroll
    for (int r = 0; r < 2; ++r) {
      const int seg = r * 256 + tid;
      const int krow = seg >> 3, ko = (seg & 7) * 8;
      gload16(&Ks[(r * 256 + wave * 64) * 8], &Kg[(size_t)(kv0 + krow) * W3 + h * 64 + ko]);
    }
#pragma unroll
    for (int r = 0; r < 2; ++r) {
      const int vrow = r * 32 + (tid >> 3);
      const int dch = (tid & 7) * 8;
      bf16x8 vv = *(const bf16x8*)&Vg[(size_t)(kv0 + vrow) * W3 + h * 64 + dch];
#pragma unroll
      for (int j = 0; j < 8; ++j) Vt[(dch + j) * 64 + vrow] = vv[j];
    }
    __syncthreads();

    if (kv0 <= qmax) {
      f32x4 s[2][4] = {};
#pragma unroll
      for (int kk = 0; kk < 2; ++kk) {
        bf16x8 kb[4];
#pragma unroll
        for (int n = 0; n < 4; ++n)
          kb[n] = *(const bf16x8*)&Ks[(n * 16 + l16) * 64 + kk * 32 + g * 8];
#pragma unroll
        for (int m = 0; m < 2; ++m)
#pragma unroll
          for (int n = 0; n < 4; ++n)
            s[m][n] = __builtin_amdgcn_mfma_f32_16x16x32_bf16(qa[m][kk], kb[n], s[m][n], 0, 0, 0);
      }
#pragma unroll
      for (int m = 0; m < 2; ++m) {
        float rmx[4] = {-1e30f, -1e30f, -1e30f, -1e30f};
#pragma unroll
        for (int n = 0; n < 4; ++n) {
          const int kc = kv0 + n * 16 + l16;
#pragma unroll
          for (int r = 0; r < 4; ++r) {
            const int qr = q0 + wave * 32 + m * 16 + g * 4 + r;
            float v = s[m][n][r] * 0.125f;
            if (kc > qr) v = -1e30f;
            s[m][n][r] = v;
            rmx[r] = fmaxf(rmx[r], v);
          }
        }
#pragma unroll
        for (int r = 0; r < 4; ++r) {
#pragma unroll
          for (int off = 1; off < 16; off <<= 1)
            rmx[r] = fmaxf(rmx[r], __shfl_xor(rmx[r], off));
          const float mnew = fmaxf(mr[m][r], rmx[r]);
          const float f = __expf(mr[m][r] - mnew);
          mr[m][r] = mnew;
          lr[m][r] *= f;
#pragma unroll
          for (int n2 = 0; n2 < 4; ++n2) o[m][n2][r] *= f;
        }
        float rsum[4] = {0.f, 0.f, 0.f, 0.f};
#pragma unroll
        for (int n = 0; n < 4; ++n)
#pragma unroll
          for (int r = 0; r < 4; ++r) {
            const float p = __expf(s[m][n][r] - mr[m][r]);
            s[m][n][r] = p;
            rsum[r] += p;
          }
#pragma unroll
        for (int r = 0; r < 4; ++r) {
#pragma unroll
          for (int off = 1; off < 16; off <<= 1)
            rsum[r] += __shfl_xor(rsum[r], off);
          lr[m][r] += rsum[r];
        }
#pragma unroll
        for (int n = 0; n < 4; ++n)
#pragma unroll
          for (int r = 0; r < 4; ++r)
            Ps[wave][(m * 16 + g * 4 + r) * 64 + n * 16 + l16] = (__bf16)s[m][n][r];
      }
#pragma unroll
      for (int kk = 0; kk < 2; ++kk) {
        bf16x8 pa[2], vb[4];
#pragma unroll
        for (int m = 0; m < 2; ++m)
          pa[m] = *(const bf16x8*)&Ps[wave][(m * 16 + l16) * 64 + kk * 32 + g * 8];
#pragma unroll
        for (int n2 = 0; n2 < 4; ++n2)
          vb[n2] = *(const bf16x8*)&Vt[(n2 * 16 + l16) * 64 + kk * 32 + g * 8];
#pragma unroll
        for (int m = 0; m < 2; ++m)
#pragma unroll
          for (int n2 = 0; n2 < 4; ++n2)
            o[m][n2] = __builtin_amdgcn_mfma_f32_16x16x32_bf16(pa[m], vb[n2], o[m][n2], 0, 0, 0);
      }
    }
  }
#pragma unroll
  for (int m = 0; m < 2; ++m)
#pragma unroll
    for (int n2 = 0; n2 < 4; ++n2)
#pragma unroll
      for (int r = 0; r < 4; ++r) {
        const int qr = q0 + wave * 32 + m * 16 + g * 4 + r;
        const int d = n2 * 16 + l16;
        ctx[(size_t)(b * S + qr) * H + h * 64 + d] = (__bf16)(o[m][n2][r] / lr[m][r]);
      }
}

// ---------------- LayerNorm over rows of 1024 ----------------
template<bool WRITE_BF16>
__global__ __launch_bounds__(256)
void ln_kernel(const float* __restrict__ in, const float* __restrict__ gw,
               const float* __restrict__ bw, float* __restrict__ outf,
               __bf16* __restrict__ outb)
{
  const int row = blockIdx.x, tid = threadIdx.x;
  const float4 xv = ((const float4*)(in + (size_t)row * 1024))[tid];
  float s = xv.x + xv.y + xv.z + xv.w;
  float s2 = xv.x * xv.x + xv.y * xv.y + xv.z * xv.z + xv.w * xv.w;
#pragma unroll
  for (int off = 32; off; off >>= 1) { s += __shfl_xor(s, off); s2 += __shfl_xor(s2, off); }
  __shared__ float ps[8];
  if ((tid & 63) == 0) { ps[tid >> 6] = s; ps[4 + (tid >> 6)] = s2; }
  __syncthreads();
  s = ps[0] + ps[1] + ps[2] + ps[3];
  s2 = ps[4] + ps[5] + ps[6] + ps[7];
  const float mean = s * (1.f / 1024.f);
  const float var = s2 * (1.f / 1024.f) - mean * mean;
  const float rs = rsqrtf(var + 1e-5f);
  const float4 gv = ((const float4*)gw)[tid];
  const float4 bv = ((const float4*)bw)[tid];
  float4 y;
  y.x = (xv.x - mean) * rs * gv.x + bv.x;
  y.y = (xv.y - mean) * rs * gv.y + bv.y;
  y.z = (xv.z - mean) * rs * gv.z + bv.z;
  y.w = (xv.w - mean) * rs * gv.w + bv.w;
  ((float4*)(outf + (size_t)row * 1024))[tid] = y;
  if (WRITE_BF16) {
    __bf16* ob = outb + (size_t)row * 1024 + tid * 4;
    ob[0] = (__bf16)y.x; ob[1] = (__bf16)y.y; ob[2] = (__bf16)y.z; ob[3] = (__bf16)y.w;
  }
}

extern "C" void kernel_launch(void* const* d_in, const int* in_sizes, int n_in,
                              void* d_out, int out_size, void* d_ws, size_t ws_size,
                              hipStream_t stream)
{
  (void)in_sizes; (void)n_in; (void)out_size; (void)ws_size;
  const float* x     = (const float*)d_in[0];
  const float* qkv_w = (const float*)d_in[2];
  const float* qkv_b = (const float*)d_in[3];
  const float* out_w = (const float*)d_in[4];
  const float* out_b = (const float*)d_in[5];
  const float* w1    = (const float*)d_in[6];
  const float* b1    = (const float*)d_in[7];
  const float* w2    = (const float*)d_in[8];
  const float* b2    = (const float*)d_in[9];
  const float* ln1g  = (const float*)d_in[10];
  const float* ln1b  = (const float*)d_in[11];
  const float* ln2g  = (const float*)d_in[12];
  const float* ln2b  = (const float*)d_in[13];

  char* ws = (char*)d_ws;
  __bf16* wt_qkv = (__bf16*)(ws + 0);          // [3072][1024] 6291456 B
  __bf16* wt_out = (__bf16*)(ws + 6291456);    // [1024][1024] 2097152 B
  __bf16* wt_w1  = (__bf16*)(ws + 8388608);    // [4096][1024] 8388608 B
  __bf16* wt_w2  = (__bf16*)(ws + 16777216);   // [1024][4096] 8388608 B
  __bf16* xb     = (__bf16*)(ws + 25165824);   // x bf16, then ctx   8388608 B
  __bf16* big    = (__bf16*)(ws + 33554432);   // qkv, then h1       33554432 B
  float*  res    = (float*)(ws + 67108864);    // res1, then res2    16777216 B
  float*  x1f    = (float*)(ws + 83886080);    // ln1 out fp32       16777216 B
  __bf16* x1b    = (__bf16*)(ws + 100663296);  // ln1 out bf16       8388608 B

  transpose_cast<<<dim3(96, 32), 256, 0, stream>>>(qkv_w, wt_qkv, 1024, 3072);
  transpose_cast<<<dim3(32, 32), 256, 0, stream>>>(out_w, wt_out, 1024, 1024);
  transpose_cast<<<dim3(128, 32), 256, 0, stream>>>(w1, wt_w1, 1024, 4096);
  transpose_cast<<<dim3(32, 128), 256, 0, stream>>>(w2, wt_w2, 4096, 1024);
  cast_bf16<<<4096, 256, 0, stream>>>(x, xb);

  // QKV: [4096][3072] bf16
  gemm_bt<true, false, false><<<dim3(32, 24), 256, 0, stream>>>(xb, wt_qkv, qkv_b, nullptr, big, 4096, 3072, 1024);
  // attention -> ctx (reuses xb)
  attn_fwd<<<dim3(16, 32), 256, 0, stream>>>(big, xb);
  // out proj + residual(x) -> res1 fp32
  gemm_bt<false, false, true><<<dim3(32, 8), 256, 0, stream>>>(xb, wt_out, out_b, x, res, 4096, 1024, 1024);
  // LN1 -> x1f fp32, x1b bf16
  ln_kernel<true><<<4096, 256, 0, stream>>>(res, ln1g, ln1b, x1f, x1b);
  // FFN1 + ReLU -> h1 bf16 (reuses big)
  gemm_bt<true, true, false><<<dim3(32, 32), 256, 0, stream>>>(x1b, wt_w1, b1, nullptr, big, 4096, 4096, 1024);
  // FFN2 + residual(x1f) -> res2 fp32 (reuses res)
  gemm_bt<false, false, true><<<dim3(32, 8), 256, 0, stream>>>(big, wt_w2, b2, x1f, res, 4096, 1024, 4096);
  // LN2 -> d_out fp32
  ln_kernel<false><<<4096, 256, 0, stream>>>(res, ln2g, ln2b, (float*)d_out, nullptr);
}

// Round 2
// 318.378 us; speedup vs baseline: 1.2956x; 1.2956x over previous
//
#include <hip/hip_runtime.h>
#include <hip/hip_bf16.h>

typedef __bf16 bf16x8 __attribute__((ext_vector_type(8)));
typedef float f32x4 __attribute__((ext_vector_type(4)));

__device__ __forceinline__ void gload16(void* lds, const void* g) {
  __builtin_amdgcn_global_load_lds((const __attribute__((address_space(1))) void*)g,
                                   (__attribute__((address_space(3))) void*)lds, 16, 0, 0);
}

// ---------------- weight cast+transpose: in [R][C] fp32 -> out [C][R] bf16 ----------------
__global__ __launch_bounds__(256)
void transpose_cast(const float* __restrict__ in, __bf16* __restrict__ out, int R, int C)
{
  __shared__ __bf16 tile[32][33];
  const int bc = blockIdx.x * 32, br = blockIdx.y * 32;
  const int lx = threadIdx.x & 31, ly = threadIdx.x >> 5;
#pragma unroll
  for (int p = 0; p < 4; ++p)
    tile[ly + p * 8][lx] = (__bf16)in[(size_t)(br + ly + p * 8) * C + bc + lx];
  __syncthreads();
#pragma unroll
  for (int p = 0; p < 4; ++p)
    out[(size_t)(bc + ly + p * 8) * R + br + lx] = tile[lx][ly + p * 8];
}

// ---------------- V transpose (bf16): qkv [B*S][3072] -> vtg [BH][64][2048] ----------------
__global__ __launch_bounds__(256)
void vtrans(const __bf16* __restrict__ qkv, __bf16* __restrict__ vtg)
{
  __shared__ __bf16 tile[32][33];
  const int sx = blockIdx.x * 32;   // s tile
  const int dy = blockIdx.y * 32;   // d tile (0 or 32)
  const int z = blockIdx.z;         // bh
  const int b = z >> 4, h = z & 15;
  const int lx = threadIdx.x & 31, ly = threadIdx.x >> 5;
  const __bf16* src = qkv + (size_t)b * 2048 * 3072 + 2048 + h * 64;
#pragma unroll
  for (int p = 0; p < 4; ++p)
    tile[ly + p * 8][lx] = src[(size_t)(sx + ly + p * 8) * 3072 + dy + lx];
  __syncthreads();
  __bf16* dst = vtg + (size_t)z * 64 * 2048;
#pragma unroll
  for (int p = 0; p < 4; ++p)
    dst[(size_t)(dy + ly + p * 8) * 2048 + sx + lx] = tile[lx][ly + p * 8];
}

// ---------------- elementwise cast fp32 -> bf16 ----------------
__global__ __launch_bounds__(256)
void cast_bf16(const float* __restrict__ in, __bf16* __restrict__ out)
{
  const int i = (blockIdx.x * 256 + threadIdx.x) * 4;
  float4 v = *(const float4*)(in + i);
  out[i] = (__bf16)v.x; out[i + 1] = (__bf16)v.y;
  out[i + 2] = (__bf16)v.z; out[i + 3] = (__bf16)v.w;
}

// ---------------- bf16 MFMA GEMM, BK=64, XOR-swizzled LDS ----------------
template<bool OUT_BF16, bool RELU, bool RESID>
__global__ __launch_bounds__(256)
void gemm_bt(const __bf16* __restrict__ A, const __bf16* __restrict__ Bt,
             const float* __restrict__ bias, const float* __restrict__ resid,
             void* __restrict__ Cv, int M, int N, int K)
{
  __shared__ __bf16 As[128 * 64];
  __shared__ __bf16 Bs[128 * 64];
  const int tid = threadIdx.x;
  const int wave = tid >> 6, lane = tid & 63;
  const int g = lane >> 4, l16 = lane & 15;
  const int row0 = blockIdx.x * 128, col0 = blockIdx.y * 128;
  const int wr = wave >> 1, wc = wave & 1;
  f32x4 acc[4][4] = {};
  for (int k0 = 0; k0 < K; k0 += 64) {
    __syncthreads();
#pragma unroll
    for (int r = 0; r < 4; ++r) {
      const int seg = r * 256 + tid;
      const int arow = seg >> 3;
      const int ko = ((seg & 7) ^ (arow & 7)) * 8;   // pre-swizzled source chunk
      gload16(&As[(r * 256 + wave * 64) * 8], &A[(size_t)(row0 + arow) * K + k0 + ko]);
      gload16(&Bs[(r * 256 + wave * 64) * 8], &Bt[(size_t)(col0 + arow) * K + k0 + ko]);
    }
    __syncthreads();
#pragma unroll
    for (int kk = 0; kk < 2; ++kk) {
      bf16x8 af[4], bfr[4];
#pragma unroll
      for (int m = 0; m < 4; ++m) {
        const int row = wr * 64 + m * 16 + l16;
        af[m] = *(const bf16x8*)&As[row * 64 + ((kk * 32 + g * 8) ^ ((row & 7) << 3))];
      }
#pragma unroll
      for (int n = 0; n < 4; ++n) {
        const int row = wc * 64 + n * 16 + l16;
        bfr[n] = *(const bf16x8*)&Bs[row * 64 + ((kk * 32 + g * 8) ^ ((row & 7) << 3))];
      }
#pragma unroll
      for (int m = 0; m < 4; ++m)
#pragma unroll
        for (int n = 0; n < 4; ++n)
          acc[m][n] = __builtin_amdgcn_mfma_f32_16x16x32_bf16(af[m], bfr[n], acc[m][n], 0, 0, 0);
    }
  }
#pragma unroll
  for (int n = 0; n < 4; ++n) {
    const int col = col0 + wc * 64 + n * 16 + l16;
    const float bv = bias[col];
#pragma unroll
    for (int m = 0; m < 4; ++m) {
      const int rrow = row0 + wr * 64 + m * 16 + g * 4;
#pragma unroll
      for (int r = 0; r < 4; ++r) {
        float v = acc[m][n][r] + bv;
        if (RESID) v += resid[(size_t)(rrow + r) * N + col];
        if (RELU)  v = fmaxf(v, 0.f);
        if (OUT_BF16) ((__bf16*)Cv)[(size_t)(rrow + r) * N + col] = (__bf16)v;
        else          ((float*)Cv)[(size_t)(rrow + r) * N + col] = v;
      }
    }
  }
}

// ---------------- flash attention (causal), bf16 MFMA, swizzled LDS ----------------
// grid (32 bh, 16 qtile-reversed), 256 thr.
__global__ __launch_bounds__(256)
void attn_fwd(const __bf16* __restrict__ qkv, const __bf16* __restrict__ vtg,
              __bf16* __restrict__ ctx)
{
  constexpr int S = 2048, H = 1024, W3 = 3 * H;
  __shared__ __bf16 Ks[64 * 64];
  __shared__ __bf16 Vt[64 * 64];
  __shared__ __bf16 Ps[4 * 32 * 64];
  const int tid = threadIdx.x, wave = tid >> 6, lane = tid & 63;
  const int g = lane >> 4, l16 = lane & 15;
  const int qi = 15 - blockIdx.y;           // heavy tiles dispatch first
  const int q0 = qi * 128;
  const int bh = blockIdx.x;
  const int b = bh >> 4, h = bh & 15;
  const size_t base = (size_t)b * S * W3;
  const __bf16* Qg = qkv + base;
  const __bf16* Kg = qkv + base + H;
  const __bf16* Vg = vtg + (size_t)bh * 64 * S;   // [d][s]

  bf16x8 qa[2][2];
#pragma unroll
  for (int m = 0; m < 2; ++m)
#pragma unroll
    for (int kk = 0; kk < 2; ++kk)
      qa[m][kk] = *(const bf16x8*)&Qg[(size_t)(q0 + wave * 32 + m * 16 + l16) * W3 + h * 64 + kk * 32 + g * 8];

  f32x4 o[2][4] = {};
  float mr[2][4], lr[2][4];
#pragma unroll
  for (int m = 0; m < 2; ++m)
#pragma unroll
    for (int r = 0; r < 4; ++r) { mr[m][r] = -1e30f; lr[m][r] = 0.f; }

  const int qmax = q0 + wave * 32 + 31;
  const int nT = 2 * qi + 2;

  for (int t = 0; t < nT; ++t) {
    const int kv0 = t * 64;
    __syncthreads();
#pragma unroll
    for (int r = 0; r < 2; ++r) {
      const int seg = r * 256 + tid;
      const int row = seg >> 3;
      const int ko = ((seg & 7) ^ (row & 7)) * 8;   // pre-swizzled source chunk
      gload16(&Ks[(r * 256 + wave * 64) * 8], &Kg[(size_t)(kv0 + row) * W3 + h * 64 + ko]);
      gload16(&Vt[(r * 256 + wave * 64) * 8], &Vg[(size_t)row * S + kv0 + ko]);
    }
    __syncthreads();

    if (kv0 <= qmax) {
      f32x4 s[2][4] = {};
#pragma unroll
      for (int kk = 0; kk < 2; ++kk) {
        bf16x8 kb[4];
#pragma unroll
        for (int n = 0; n < 4; ++n) {
          const int row = n * 16 + l16;
          kb[n] = *(const bf16x8*)&Ks[row * 64 + ((kk * 32 + g * 8) ^ ((row & 7) << 3))];
        }
#pragma unroll
        for (int m = 0; m < 2; ++m)
#pragma unroll
          for (int n = 0; n < 4; ++n)
            s[m][n] = __builtin_amdgcn_mfma_f32_16x16x32_bf16(qa[m][kk], kb[n], s[m][n], 0, 0, 0);
      }
      const bool domask = (t >= nT - 2);
#pragma unroll
      for (int m = 0; m < 2; ++m) {
        float rmx[4] = {-1e30f, -1e30f, -1e30f, -1e30f};
#pragma unroll
        for (int n = 0; n < 4; ++n) {
          const int kc = kv0 + n * 16 + l16;
#pragma unroll
          for (int r = 0; r < 4; ++r) {
            const int qr = q0 + wave * 32 + m * 16 + g * 4 + r;
            float v = s[m][n][r] * 0.125f;
            if (domask && kc > qr) v = -1e30f;
            s[m][n][r] = v;
            rmx[r] = fmaxf(rmx[r], v);
          }
        }
#pragma unroll
        for (int r = 0; r < 4; ++r) {
#pragma unroll
          for (int off = 1; off < 16; off <<= 1)
            rmx[r] = fmaxf(rmx[r], __shfl_xor(rmx[r], off));
          const float mnew = fmaxf(mr[m][r], rmx[r]);
          const float f = __expf(mr[m][r] - mnew);
          mr[m][r] = mnew;
          lr[m][r] *= f;
#pragma unroll
          for (int n2 = 0; n2 < 4; ++n2) o[m][n2][r] *= f;
        }
        float rsum[4] = {0.f, 0.f, 0.f, 0.f};
#pragma unroll
        for (int n = 0; n < 4; ++n)
#pragma unroll
          for (int r = 0; r < 4; ++r) {
            const float p = __expf(s[m][n][r] - mr[m][r]);
            s[m][n][r] = p;
            rsum[r] += p;
          }
#pragma unroll
        for (int r = 0; r < 4; ++r) {
#pragma unroll
          for (int off = 1; off < 16; off <<= 1)
            rsum[r] += __shfl_xor(rsum[r], off);
          lr[m][r] += rsum[r];
        }
#pragma unroll
        for (int n = 0; n < 4; ++n)
#pragma unroll
          for (int r = 0; r < 4; ++r) {
            const int rr = m * 16 + g * 4 + r;
            Ps[wave * 2048 + rr * 64 + ((n * 16 + l16) ^ ((rr & 7) << 3))] = (__bf16)s[m][n][r];
          }
      }
#pragma unroll
      for (int kk = 0; kk < 2; ++kk) {
        bf16x8 pa[2], vb[4];
#pragma unroll
        for (int m = 0; m < 2; ++m) {
          const int rowp = m * 16 + l16;
          pa[m] = *(const bf16x8*)&Ps[wave * 2048 + rowp * 64 + ((kk * 32 + g * 8) ^ ((rowp & 7) << 3))];
        }
#pragma unroll
        for (int n2 = 0; n2 < 4; ++n2) {
          const int row = n2 * 16 + l16;
          vb[n2] = *(const bf16x8*)&Vt[row * 64 + ((kk * 32 + g * 8) ^ ((row & 7) << 3))];
        }
#pragma unroll
        for (int m = 0; m < 2; ++m)
#pragma unroll
          for (int n2 = 0; n2 < 4; ++n2)
            o[m][n2] = __builtin_amdgcn_mfma_f32_16x16x32_bf16(pa[m], vb[n2], o[m][n2], 0, 0, 0);
      }
    }
  }
#pragma unroll
  for (int m = 0; m < 2; ++m)
#pragma unroll
    for (int n2 = 0; n2 < 4; ++n2)
#pragma unroll
      for (int r = 0; r < 4; ++r) {
        const int qr = q0 + wave * 32 + m * 16 + g * 4 + r;
        const int d = n2 * 16 + l16;
        ctx[(size_t)(b * S + qr) * H + h * 64 + d] = (__bf16)(o[m][n2][r] / lr[m][r]);
      }
}

// ---------------- LayerNorm over rows of 1024 ----------------
template<bool WRITE_BF16>
__global__ __launch_bounds__(256)
void ln_kernel(const float* __restrict__ in, const float* __restrict__ gw,
               const float* __restrict__ bw, float* __restrict__ outf,
               __bf16* __restrict__ outb)
{
  const int row = blockIdx.x, tid = threadIdx.x;
  const float4 xv = ((const float4*)(in + (size_t)row * 1024))[tid];
  float s = xv.x + xv.y + xv.z + xv.w;
  float s2 = xv.x * xv.x + xv.y * xv.y + xv.z * xv.z + xv.w * xv.w;
#pragma unroll
  for (int off = 32; off; off >>= 1) { s += __shfl_xor(s, off); s2 += __shfl_xor(s2, off); }
  __shared__ float ps[8];
  if ((tid & 63) == 0) { ps[tid >> 6] = s; ps[4 + (tid >> 6)] = s2; }
  __syncthreads();
  s = ps[0] + ps[1] + ps[2] + ps[3];
  s2 = ps[4] + ps[5] + ps[6] + ps[7];
  const float mean = s * (1.f / 1024.f);
  const float var = s2 * (1.f / 1024.f) - mean * mean;
  const float rs = rsqrtf(var + 1e-5f);
  const float4 gv = ((const float4*)gw)[tid];
  const float4 bv = ((const float4*)bw)[tid];
  float4 y;
  y.x = (xv.x - mean) * rs * gv.x + bv.x;
  y.y = (xv.y - mean) * rs * gv.y + bv.y;
  y.z = (xv.z - mean) * rs * gv.z + bv.z;
  y.w = (xv.w - mean) * rs * gv.w + bv.w;
  ((float4*)(outf + (size_t)row * 1024))[tid] = y;
  if (WRITE_BF16) {
    __bf16* ob = outb + (size_t)row * 1024 + tid * 4;
    ob[0] = (__bf16)y.x; ob[1] = (__bf16)y.y; ob[2] = (__bf16)y.z; ob[3] = (__bf16)y.w;
  }
}

extern "C" void kernel_launch(void* const* d_in, const int* in_sizes, int n_in,
                              void* d_out, int out_size, void* d_ws, size_t ws_size,
                              hipStream_t stream)
{
  (void)in_sizes; (void)n_in; (void)out_size; (void)ws_size;
  const float* x     = (const float*)d_in[0];
  const float* qkv_w = (const float*)d_in[2];
  const float* qkv_b = (const float*)d_in[3];
  const float* out_w = (const float*)d_in[4];
  const float* out_b = (const float*)d_in[5];
  const float* w1    = (const float*)d_in[6];
  const float* b1    = (const float*)d_in[7];
  const float* w2    = (const float*)d_in[8];
  const float* b2    = (const float*)d_in[9];
  const float* ln1g  = (const float*)d_in[10];
  const float* ln1b  = (const float*)d_in[11];
  const float* ln2g  = (const float*)d_in[12];
  const float* ln2b  = (const float*)d_in[13];

  char* ws = (char*)d_ws;
  __bf16* wt_qkv = (__bf16*)(ws + 0);          // [3072][1024] 6291456 B
  __bf16* wt_out = (__bf16*)(ws + 6291456);    // [1024][1024] 2097152 B
  __bf16* wt_w1  = (__bf16*)(ws + 8388608);    // [4096][1024] 8388608 B
  __bf16* wt_w2  = (__bf16*)(ws + 16777216);   // [1024][4096] 8388608 B
  __bf16* xb     = (__bf16*)(ws + 25165824);   // x bf16, then ctx   8388608 B
  __bf16* big    = (__bf16*)(ws + 33554432);   // qkv, then h1       33554432 B
  float*  res    = (float*)(ws + 67108864);    // Vt_g (attn) then res1/res2  16777216 B
  float*  x1f    = (float*)(ws + 83886080);    // ln1 out fp32       16777216 B
  __bf16* x1b    = (__bf16*)(ws + 100663296);  // ln1 out bf16       8388608 B
  __bf16* vtg    = (__bf16*)res;               // [32][64][2048] 8388608 B (dead after attn)

  transpose_cast<<<dim3(96, 32), 256, 0, stream>>>(qkv_w, wt_qkv, 1024, 3072);
  transpose_cast<<<dim3(32, 32), 256, 0, stream>>>(out_w, wt_out, 1024, 1024);
  transpose_cast<<<dim3(128, 32), 256, 0, stream>>>(w1, wt_w1, 1024, 4096);
  transpose_cast<<<dim3(32, 128), 256, 0, stream>>>(w2, wt_w2, 4096, 1024);
  cast_bf16<<<4096, 256, 0, stream>>>(x, xb);

  // QKV: [4096][3072] bf16
  gemm_bt<true, false, false><<<dim3(32, 24), 256, 0, stream>>>(xb, wt_qkv, qkv_b, nullptr, big, 4096, 3072, 1024);
  // V -> V^T per (b,h)
  vtrans<<<dim3(64, 2, 32), 256, 0, stream>>>(big, vtg);
  // attention -> ctx (reuses xb)
  attn_fwd<<<dim3(32, 16), 256, 0, stream>>>(big, vtg, xb);
  // out proj + residual(x) -> res1 fp32
  gemm_bt<false, false, true><<<dim3(32, 8), 256, 0, stream>>>(xb, wt_out, out_b, x, res, 4096, 1024, 1024);
  // LN1 -> x1f fp32, x1b bf16
  ln_kernel<true><<<4096, 256, 0, stream>>>(res, ln1g, ln1b, x1f, x1b);
  // FFN1 + ReLU -> h1 bf16 (reuses big)
  gemm_bt<true, true, false><<<dim3(32, 32), 256, 0, stream>>>(x1b, wt_w1, b1, nullptr, big, 4096, 4096, 1024);
  // FFN2 + residual(x1f) -> res2 fp32 (reuses res)
  gemm_bt<false, false, true><<<dim3(32, 8), 256, 0, stream>>>(big, wt_w2, b2, x1f, res, 4096, 1024, 4096);
  // LN2 -> d_out fp32
  ln_kernel<false><<<4096, 256, 0, stream>>>(res, ln2g, ln2b, (float*)d_out, nullptr);
}

// Round 3
// 262.299 us; speedup vs baseline: 1.5726x; 1.2138x over previous
//
#include <hip/hip_runtime.h>
#include <hip/hip_bf16.h>

typedef __bf16 bf16x8 __attribute__((ext_vector_type(8)));
typedef float f32x4 __attribute__((ext_vector_type(4)));

__device__ __forceinline__ void gload16(void* lds, const void* g) {
  __builtin_amdgcn_global_load_lds((const __attribute__((address_space(1))) void*)g,
                                   (__attribute__((address_space(3))) void*)lds, 16, 0, 0);
}

// ---------------- weight cast+transpose: in [R][C] fp32 -> out [C][R] bf16 ----------------
__global__ __launch_bounds__(256)
void transpose_cast(const float* __restrict__ in, __bf16* __restrict__ out, int R, int C)
{
  __shared__ __bf16 tile[32][33];
  const int bc = blockIdx.x * 32, br = blockIdx.y * 32;
  const int lx = threadIdx.x & 31, ly = threadIdx.x >> 5;
#pragma unroll
  for (int p = 0; p < 4; ++p)
    tile[ly + p * 8][lx] = (__bf16)in[(size_t)(br + ly + p * 8) * C + bc + lx];
  __syncthreads();
#pragma unroll
  for (int p = 0; p < 4; ++p)
    out[(size_t)(bc + ly + p * 8) * R + br + lx] = tile[lx][ly + p * 8];
}

// ---------------- V transpose (bf16): qkv [B*S][3072] -> vtg [BH][64][2048] ----------------
__global__ __launch_bounds__(256)
void vtrans(const __bf16* __restrict__ qkv, __bf16* __restrict__ vtg)
{
  __shared__ __bf16 tile[32][33];
  const int sx = blockIdx.x * 32;
  const int dy = blockIdx.y * 32;
  const int z = blockIdx.z;
  const int b = z >> 4, h = z & 15;
  const int lx = threadIdx.x & 31, ly = threadIdx.x >> 5;
  const __bf16* src = qkv + (size_t)b * 2048 * 3072 + 2048 + h * 64;
#pragma unroll
  for (int p = 0; p < 4; ++p)
    tile[ly + p * 8][lx] = src[(size_t)(sx + ly + p * 8) * 3072 + dy + lx];
  __syncthreads();
  __bf16* dst = vtg + (size_t)z * 64 * 2048;
#pragma unroll
  for (int p = 0; p < 4; ++p)
    dst[(size_t)(dy + ly + p * 8) * 2048 + sx + lx] = tile[lx][ly + p * 8];
}

// ---------------- elementwise cast fp32 -> bf16 ----------------
__global__ __launch_bounds__(256)
void cast_bf16(const float* __restrict__ in, __bf16* __restrict__ out)
{
  const int i = (blockIdx.x * 256 + threadIdx.x) * 4;
  float4 v = *(const float4*)(in + i);
  out[i] = (__bf16)v.x; out[i + 1] = (__bf16)v.y;
  out[i + 2] = (__bf16)v.z; out[i + 3] = (__bf16)v.w;
}

// ---------------- bf16 MFMA GEMM, BK=64, XOR-swizzled LDS, 2-phase dbuf ----------------
template<int BN, bool OUT_BF16, bool RELU, bool RESID>
__global__ __launch_bounds__(256)
void gemm_bt(const __bf16* __restrict__ A, const __bf16* __restrict__ Bt,
             const float* __restrict__ bias, const float* __restrict__ resid,
             void* __restrict__ Cv, int M, int N, int K)
{
  constexpr int NW = BN / 32;   // acc cols per wave
  __shared__ __bf16 As[2][128 * 64];
  __shared__ __bf16 Bs[2][BN * 64];
  const int tid = threadIdx.x;
  const int wave = tid >> 6, lane = tid & 63;
  const int g = lane >> 4, l16 = lane & 15;
  const int row0 = blockIdx.x * 128, col0 = blockIdx.y * BN;
  const int wr = wave >> 1, wc = wave & 1;
  f32x4 acc[4][NW] = {};
  const int nk = K >> 6;

  auto STAGE = [&](int buf, int k0) {
#pragma unroll
    for (int r = 0; r < 4; ++r) {
      const int seg = r * 256 + tid;
      const int arow = seg >> 3;
      const int ko = ((seg & 7) ^ (arow & 7)) * 8;
      gload16(&As[buf][(r * 256 + wave * 64) * 8], &A[(size_t)(row0 + arow) * K + k0 + ko]);
    }
#pragma unroll
    for (int r = 0; r < BN / 32; ++r) {
      const int seg = r * 256 + tid;
      const int brow = seg >> 3;
      const int ko = ((seg & 7) ^ (brow & 7)) * 8;
      gload16(&Bs[buf][(r * 256 + wave * 64) * 8], &Bt[(size_t)(col0 + brow) * K + k0 + ko]);
    }
  };

  STAGE(0, 0);
  __syncthreads();
  int cur = 0;
  for (int t = 0; t < nk; ++t) {
    if (t + 1 < nk) STAGE(cur ^ 1, (t + 1) << 6);
#pragma unroll
    for (int kk = 0; kk < 2; ++kk) {
      bf16x8 af[4], bfr[NW];
#pragma unroll
      for (int m = 0; m < 4; ++m) {
        const int row = wr * 64 + m * 16 + l16;
        af[m] = *(const bf16x8*)&As[cur][row * 64 + ((kk * 32 + g * 8) ^ ((row & 7) << 3))];
      }
#pragma unroll
      for (int n = 0; n < NW; ++n) {
        const int row = wc * (BN / 2) + n * 16 + l16;
        bfr[n] = *(const bf16x8*)&Bs[cur][row * 64 + ((kk * 32 + g * 8) ^ ((row & 7) << 3))];
      }
#pragma unroll
      for (int m = 0; m < 4; ++m)
#pragma unroll
        for (int n = 0; n < NW; ++n)
          acc[m][n] = __builtin_amdgcn_mfma_f32_16x16x32_bf16(af[m], bfr[n], acc[m][n], 0, 0, 0);
    }
    __syncthreads();
    cur ^= 1;
  }
#pragma unroll
  for (int n = 0; n < NW; ++n) {
    const int col = col0 + wc * (BN / 2) + n * 16 + l16;
    const float bv = bias[col];
#pragma unroll
    for (int m = 0; m < 4; ++m) {
      const int rrow = row0 + wr * 64 + m * 16 + g * 4;
#pragma unroll
      for (int r = 0; r < 4; ++r) {
        float v = acc[m][n][r] + bv;
        if (RESID) v += resid[(size_t)(rrow + r) * N + col];
        if (RELU)  v = fmaxf(v, 0.f);
        if (OUT_BF16) ((__bf16*)Cv)[(size_t)(rrow + r) * N + col] = (__bf16)v;
        else          ((float*)Cv)[(size_t)(rrow + r) * N + col] = v;
      }
    }
  }
}

// ---------------- flash attention (causal), QBLK=64, dbuf K/V, swizzled LDS ----------------
// grid (32 bh, 32 qtile-reversed), 256 thr; wave owns 16 q-rows.
__global__ __launch_bounds__(256)
void attn_fwd(const __bf16* __restrict__ qkv, const __bf16* __restrict__ vtg,
              __bf16* __restrict__ ctx)
{
  constexpr int S = 2048, H = 1024, W3 = 3 * H;
  __shared__ __bf16 Ks[2][64 * 64];
  __shared__ __bf16 Vt[2][64 * 64];
  __shared__ __bf16 Ps[4][16 * 64];
  const int tid = threadIdx.x, wave = tid >> 6, lane = tid & 63;
  const int g = lane >> 4, l16 = lane & 15;
  const int qi = 31 - blockIdx.y;           // heavy tiles dispatch first
  const int q0 = qi * 64;
  const int bh = blockIdx.x;
  const int b = bh >> 4, h = bh & 15;
  const size_t base = (size_t)b * S * W3;
  const __bf16* Qg = qkv + base;
  const __bf16* Kg = qkv + base + H;
  const __bf16* Vg = vtg + (size_t)bh * 64 * S;   // [d][s]

  const int qrow = q0 + wave * 16 + l16;
  bf16x8 qa[2];
#pragma unroll
  for (int kk = 0; kk < 2; ++kk)
    qa[kk] = *(const bf16x8*)&Qg[(size_t)qrow * W3 + h * 64 + kk * 32 + g * 8];

  f32x4 o[4] = {};
  float mr[4], lr[4];
#pragma unroll
  for (int r = 0; r < 4; ++r) { mr[r] = -1e30f; lr[r] = 0.f; }

  const int nT = qi + 1;

  auto STAGE_KV = [&](int buf, int kv0) {
#pragma unroll
    for (int r = 0; r < 2; ++r) {
      const int seg = r * 256 + tid;
      const int row = seg >> 3;
      const int ko = ((seg & 7) ^ (row & 7)) * 8;
      gload16(&Ks[buf][(r * 256 + wave * 64) * 8], &Kg[(size_t)(kv0 + row) * W3 + h * 64 + ko]);
      gload16(&Vt[buf][(r * 256 + wave * 64) * 8], &Vg[(size_t)row * S + kv0 + ko]);
    }
  };

  STAGE_KV(0, 0);
  __syncthreads();
  int cur = 0;

  for (int t = 0; t < nT; ++t) {
    const int kv0 = t * 64;
    if (t + 1 < nT) STAGE_KV(cur ^ 1, kv0 + 64);

    f32x4 s[4] = {};
#pragma unroll
    for (int kk = 0; kk < 2; ++kk) {
      bf16x8 kb[4];
#pragma unroll
      for (int n = 0; n < 4; ++n) {
        const int row = n * 16 + l16;
        kb[n] = *(const bf16x8*)&Ks[cur][row * 64 + ((kk * 32 + g * 8) ^ ((row & 7) << 3))];
      }
#pragma unroll
      for (int n = 0; n < 4; ++n)
        s[n] = __builtin_amdgcn_mfma_f32_16x16x32_bf16(qa[kk], kb[n], s[n], 0, 0, 0);
    }

    const bool domask = (t == nT - 1);
    float rmx[4] = {-1e30f, -1e30f, -1e30f, -1e30f};
#pragma unroll
    for (int n = 0; n < 4; ++n) {
      const int kc = kv0 + n * 16 + l16;
#pragma unroll
      for (int r = 0; r < 4; ++r) {
        const int qr = q0 + wave * 16 + g * 4 + r;
        float v = s[n][r] * 0.125f;
        if (domask && kc > qr) v = -1e30f;
        s[n][r] = v;
        rmx[r] = fmaxf(rmx[r], v);
      }
    }
#pragma unroll
    for (int r = 0; r < 4; ++r) {
#pragma unroll
      for (int off = 1; off < 16; off <<= 1)
        rmx[r] = fmaxf(rmx[r], __shfl_xor(rmx[r], off));
      const float mnew = fmaxf(mr[r], rmx[r]);
      const float f = __expf(mr[r] - mnew);
      mr[r] = mnew;
      lr[r] *= f;
#pragma unroll
      for (int n2 = 0; n2 < 4; ++n2) o[n2][r] *= f;
    }
    float rsum[4] = {0.f, 0.f, 0.f, 0.f};
#pragma unroll
    for (int n = 0; n < 4; ++n)
#pragma unroll
      for (int r = 0; r < 4; ++r) {
        const float p = __expf(s[n][r] - mr[r]);
        s[n][r] = p;
        rsum[r] += p;
      }
#pragma unroll
    for (int r = 0; r < 4; ++r) {
#pragma unroll
      for (int off = 1; off < 16; off <<= 1)
        rsum[r] += __shfl_xor(rsum[r], off);
      lr[r] += rsum[r];
    }
#pragma unroll
    for (int n = 0; n < 4; ++n)
#pragma unroll
      for (int r = 0; r < 4; ++r) {
        const int rr = g * 4 + r;
        Ps[wave][rr * 64 + ((n * 16 + l16) ^ ((rr & 7) << 3))] = (__bf16)s[n][r];
      }

#pragma unroll
    for (int kk = 0; kk < 2; ++kk) {
      bf16x8 pa, vb[4];
      pa = *(const bf16x8*)&Ps[wave][l16 * 64 + ((kk * 32 + g * 8) ^ ((l16 & 7) << 3))];
#pragma unroll
      for (int n2 = 0; n2 < 4; ++n2) {
        const int row = n2 * 16 + l16;
        vb[n2] = *(const bf16x8*)&Vt[cur][row * 64 + ((kk * 32 + g * 8) ^ ((row & 7) << 3))];
      }
#pragma unroll
      for (int n2 = 0; n2 < 4; ++n2)
        o[n2] = __builtin_amdgcn_mfma_f32_16x16x32_bf16(pa, vb[n2], o[n2], 0, 0, 0);
    }
    __syncthreads();
    cur ^= 1;
  }
#pragma unroll
  for (int n2 = 0; n2 < 4; ++n2)
#pragma unroll
    for (int r = 0; r < 4; ++r) {
      const int qr = q0 + wave * 16 + g * 4 + r;
      const int d = n2 * 16 + l16;
      ctx[(size_t)(b * S + qr) * H + h * 64 + d] = (__bf16)(o[n2][r] / lr[r]);
    }
}

// ---------------- LayerNorm over rows of 1024 ----------------
template<bool WRITE_BF16>
__global__ __launch_bounds__(256)
void ln_kernel(const float* __restrict__ in, const float* __restrict__ gw,
               const float* __restrict__ bw, float* __restrict__ outf,
               __bf16* __restrict__ outb)
{
  const int row = blockIdx.x, tid = threadIdx.x;
  const float4 xv = ((const float4*)(in + (size_t)row * 1024))[tid];
  float s = xv.x + xv.y + xv.z + xv.w;
  float s2 = xv.x * xv.x + xv.y * xv.y + xv.z * xv.z + xv.w * xv.w;
#pragma unroll
  for (int off = 32; off; off >>= 1) { s += __shfl_xor(s, off); s2 += __shfl_xor(s2, off); }
  __shared__ float ps[8];
  if ((tid & 63) == 0) { ps[tid >> 6] = s; ps[4 + (tid >> 6)] = s2; }
  __syncthreads();
  s = ps[0] + ps[1] + ps[2] + ps[3];
  s2 = ps[4] + ps[5] + ps[6] + ps[7];
  const float mean = s * (1.f / 1024.f);
  const float var = s2 * (1.f / 1024.f) - mean * mean;
  const float rs = rsqrtf(var + 1e-5f);
  const float4 gv = ((const float4*)gw)[tid];
  const float4 bv = ((const float4*)bw)[tid];
  float4 y;
  y.x = (xv.x - mean) * rs * gv.x + bv.x;
  y.y = (xv.y - mean) * rs * gv.y + bv.y;
  y.z = (xv.z - mean) * rs * gv.z + bv.z;
  y.w = (xv.w - mean) * rs * gv.w + bv.w;
  ((float4*)(outf + (size_t)row * 1024))[tid] = y;
  if (WRITE_BF16) {
    __bf16* ob = outb + (size_t)row * 1024 + tid * 4;
    ob[0] = (__bf16)y.x; ob[1] = (__bf16)y.y; ob[2] = (__bf16)y.z; ob[3] = (__bf16)y.w;
  }
}

extern "C" void kernel_launch(void* const* d_in, const int* in_sizes, int n_in,
                              void* d_out, int out_size, void* d_ws, size_t ws_size,
                              hipStream_t stream)
{
  (void)in_sizes; (void)n_in; (void)out_size; (void)ws_size;
  const float* x     = (const float*)d_in[0];
  const float* qkv_w = (const float*)d_in[2];
  const float* qkv_b = (const float*)d_in[3];
  const float* out_w = (const float*)d_in[4];
  const float* out_b = (const float*)d_in[5];
  const float* w1    = (const float*)d_in[6];
  const float* b1    = (const float*)d_in[7];
  const float* w2    = (const float*)d_in[8];
  const float* b2    = (const float*)d_in[9];
  const float* ln1g  = (const float*)d_in[10];
  const float* ln1b  = (const float*)d_in[11];
  const float* ln2g  = (const float*)d_in[12];
  const float* ln2b  = (const float*)d_in[13];

  char* ws = (char*)d_ws;
  __bf16* wt_qkv = (__bf16*)(ws + 0);          // [3072][1024]
  __bf16* wt_out = (__bf16*)(ws + 6291456);    // [1024][1024]
  __bf16* wt_w1  = (__bf16*)(ws + 8388608);    // [4096][1024]
  __bf16* wt_w2  = (__bf16*)(ws + 16777216);   // [1024][4096]
  __bf16* xb     = (__bf16*)(ws + 25165824);   // x bf16, then ctx
  __bf16* big    = (__bf16*)(ws + 33554432);   // qkv, then h1
  float*  res    = (float*)(ws + 67108864);    // vtg (attn) then res1/res2
  float*  x1f    = (float*)(ws + 83886080);    // ln1 out fp32
  __bf16* x1b    = (__bf16*)(ws + 100663296);  // ln1 out bf16
  __bf16* vtg    = (__bf16*)res;               // [32][64][2048] (dead after attn)

  transpose_cast<<<dim3(96, 32), 256, 0, stream>>>(qkv_w, wt_qkv, 1024, 3072);
  transpose_cast<<<dim3(32, 32), 256, 0, stream>>>(out_w, wt_out, 1024, 1024);
  transpose_cast<<<dim3(128, 32), 256, 0, stream>>>(w1, wt_w1, 1024, 4096);
  transpose_cast<<<dim3(32, 128), 256, 0, stream>>>(w2, wt_w2, 4096, 1024);
  cast_bf16<<<4096, 256, 0, stream>>>(x, xb);

  // QKV
  gemm_bt<128, true, false, false><<<dim3(32, 24), 256, 0, stream>>>(xb, wt_qkv, qkv_b, nullptr, big, 4096, 3072, 1024);
  // V -> V^T per (b,h)
  vtrans<<<dim3(64, 2, 32), 256, 0, stream>>>(big, vtg);
  // attention -> ctx (reuses xb)
  attn_fwd<<<dim3(32, 32), 256, 0, stream>>>(big, vtg, xb);
  // out proj + residual(x) -> res1 fp32
  gemm_bt<64, false, false, true><<<dim3(32, 16), 256, 0, stream>>>(xb, wt_out, out_b, x, res, 4096, 1024, 1024);
  // LN1
  ln_kernel<true><<<4096, 256, 0, stream>>>(res, ln1g, ln1b, x1f, x1b);
  // FFN1 + ReLU
  gemm_bt<128, true, true, false><<<dim3(32, 32), 256, 0, stream>>>(x1b, wt_w1, b1, nullptr, big, 4096, 4096, 1024);
  // FFN2 + residual(x1f)
  gemm_bt<64, false, false, true><<<dim3(32, 16), 256, 0, stream>>>(big, wt_w2, b2, x1f, res, 4096, 1024, 4096);
  // LN2 -> d_out
  ln_kernel<false><<<4096, 256, 0, stream>>>(res, ln2g, ln2b, (float*)d_out, nullptr);
}